// Round 6
// baseline (382.268 us; speedup 1.0000x reference)
//
#include <hip/hip_runtime.h>
#include <hip/hip_bf16.h>
#include <hip/hip_fp8.h>
#include <math.h>

// Problem constants
#define B_ROWS 4096
#define N_ROWS 8192          // 2B
#define D_DIM  1024
#define NTILES 64            // 8192 / 128
#define NSLOT  64            // partial slots per row = one per "other" tile
#define NPAIRS (NTILES * (NTILES + 1) / 2)  // 2080 upper-triangle tile pairs
#define NXCD 8

#define BM 128
#define BK 64                // fp8 elems per K-tile = 64 B per row
#define NT (D_DIM / BK)      // 16 K-tiles
#define SLOT_BYTES 16384     // A (8 KB) + B (8 KB) per ring slot
#define RING 2               // double buffer: 32 KB -> 4 blocks/CU

typedef __attribute__((ext_vector_type(4))) int i32x4;
typedef __attribute__((ext_vector_type(8))) int i32x8;
typedef __attribute__((ext_vector_type(16))) float f32x16;

#define SCALE1 0x7F7F7F7F    // E8M0 127 = 2^0 in every byte -> unit scales

__device__ __forceinline__ void load_lds_16B(const void* g, void* l) {
  __builtin_amdgcn_global_load_lds(
      (const __attribute__((address_space(1))) void*)g,
      (__attribute__((address_space(3))) void*)l, 16, 0, 0);
}

#define VMCNT0() asm volatile("s_waitcnt vmcnt(0)" ::: "memory")
#define LGKM0()  asm volatile("s_waitcnt lgkmcnt(0)" ::: "memory")
#define BARRIER() asm volatile("s_barrier" ::: "memory")

__device__ __forceinline__ float fp8dec(unsigned char b) {
  __hip_fp8_e4m3 t;
  t.__x = b;
  return (float)t;
}

// ---------------------------------------------------------------------------
// Kernel 1: row L2-normalize -> fp8 e4m3 z [8192][1024]; dn[n] = sum(q(z)^2)
// ---------------------------------------------------------------------------
__global__ void normalize_kernel(const float* __restrict__ emb_i,
                                 const float* __restrict__ emb_j,
                                 unsigned char* __restrict__ z,
                                 float* __restrict__ dn) {
  const int row = blockIdx.x;
  const int tid = threadIdx.x;  // 256 threads, 4 floats each
  const float* src = (row < B_ROWS) ? (emb_i + (size_t)row * D_DIM)
                                    : (emb_j + (size_t)(row - B_ROWS) * D_DIM);
  float4 v = reinterpret_cast<const float4*>(src)[tid];
  float ss = v.x * v.x + v.y * v.y + v.z * v.z + v.w * v.w;
#pragma unroll
  for (int m = 32; m; m >>= 1) ss += __shfl_xor(ss, m, 64);
  __shared__ float red[4];
  const int wave = tid >> 6, lane = tid & 63;
  if (lane == 0) red[wave] = ss;
  __syncthreads();
  const float tot = red[0] + red[1] + red[2] + red[3];
  const float scale = 1.0f / fmaxf(sqrtf(tot), 1e-12f);

  __hip_fp8_e4m3 q0(v.x * scale), q1(v.y * scale), q2(v.z * scale),
      q3(v.w * scale);
  uchar4 pk;
  pk.x = q0.__x;
  pk.y = q1.__x;
  pk.z = q2.__x;
  pk.w = q3.__x;
  reinterpret_cast<uchar4*>(z)[(size_t)row * (D_DIM / 4) + tid] = pk;

  const float f0 = (float)q0, f1 = (float)q1, f2 = (float)q2, f3 = (float)q3;
  float ds = f0 * f0 + f1 * f1 + f2 * f2 + f3 * f3;
#pragma unroll
  for (int m = 32; m; m >>= 1) ds += __shfl_xor(ds, m, 64);
  __syncthreads();
  if (lane == 0) red[wave] = ds;
  __syncthreads();
  if (tid == 0) dn[row] = red[0] + red[1] + red[2] + red[3];
}

// ---------------------------------------------------------------------------
// Kernel 2: pos[n] = dot(q(z[n]), q(z[n+B])) for n in [0,B)
// ---------------------------------------------------------------------------
__global__ void pos_kernel(const unsigned char* __restrict__ z,
                           float* __restrict__ pos) {
  const int n = blockIdx.x;     // 0..4095
  const int tid = threadIdx.x;  // 256
  uchar4 a = reinterpret_cast<const uchar4*>(z + (size_t)n * D_DIM)[tid];
  uchar4 b =
      reinterpret_cast<const uchar4*>(z + (size_t)(n + B_ROWS) * D_DIM)[tid];
  float s = fp8dec(a.x) * fp8dec(b.x) + fp8dec(a.y) * fp8dec(b.y) +
            fp8dec(a.z) * fp8dec(b.z) + fp8dec(a.w) * fp8dec(b.w);
#pragma unroll
  for (int m = 32; m; m >>= 1) s += __shfl_xor(s, m, 64);
  __shared__ float red[4];
  const int wave = tid >> 6, lane = tid & 63;
  if (lane == 0) red[wave] = s;
  __syncthreads();
  if (tid == 0) pos[n] = red[0] + red[1] + red[2] + red[3];
}

// ---------------------------------------------------------------------------
// Kernel 3: fused fp8 GEMM + exp + row/col-sum, symmetric tile pairs.
// Ring-2 double buffer (unchanged R4 schedule). MFMA = mfma_scale 32x32x64
// f8f6f4 (fp8 e4m3 A/B, unit E8M0 scales) -> 2x matrix rate, half LDS bytes.
//
// LDS per ring slot (16 KB): A[128][64B] at +0, B[128][64B] at +8192.
// Row r has 4 16-B slots; element slot s stored at physical slot
// s ^ ((r>>1)&3) (same involution both sides: pre-swizzled global source for
// the linear global_load_lds, swizzled ds_read offsets).
// Frag layout (32x32x64): lane l holds row (l&31), k-half (l>>5)*32..+32,
// i.e. logical slots {2*(l>>5), +1}. Any consistent k-permutation between A
// and B cancels in the dot product.
// ---------------------------------------------------------------------------
__global__ __launch_bounds__(256, 4) void simexp_kernel(
    const unsigned char* __restrict__ z, float* __restrict__ partial) {
  __shared__ __align__(16) char ldsbuf[RING * SLOT_BYTES];  // 32 KB
  __shared__ float rowAcc[BM];
  __shared__ float colAcc[BM];

  const int tid = threadIdx.x;

  // XCD-chunked bijective swizzle (2080 = 8 * 260).
  const int work = (blockIdx.x % NXCD) * (NPAIRS / NXCD) + blockIdx.x / NXCD;

  // triangular decode: work -> (ti, tj), ti <= tj
  int rem = work;
  int ti = 0;
  while (rem >= NTILES - ti) {
    rem -= NTILES - ti;
    ++ti;
  }
  const int tj = ti + rem;
  const bool diag = (ti == tj);
  const int row0 = ti * BM;
  const int m0 = tj * BM;

  if (tid < BM) rowAcc[tid] = 0.0f;
  else colAcc[tid - BM] = 0.0f;

  const int wave = tid >> 6, lane = tid & 63;
  const int wr = wave >> 1, wc = wave & 1;  // 2x2 wave grid, each 64x64
  const int l31 = lane & 31, l5 = lane >> 5;

  // ---- staging geometry (fixed per thread): identical to R4 (64-B rows) ----
  const int rs = tid >> 2;
  const int qs = tid & 3;
  const int ss = qs ^ ((rs >> 1) & 3);
  const unsigned char* gA0 = z + (size_t)(row0 + rs) * D_DIM + ss * 16;
  const unsigned char* gA1 = z + (size_t)(row0 + rs + 64) * D_DIM + ss * 16;
  const unsigned char* gB0 = z + (size_t)(m0 + rs) * D_DIM + ss * 16;
  const unsigned char* gB1 = z + (size_t)(m0 + rs + 64) * D_DIM + ss * 16;
  const int WA0 = tid * 16;
  const int WA1 = tid * 16 + 4096;

  // ---- fragment read offsets (fixed per thread) ----
  // frag mi: row rA = wr*64 + mi*32 + l31; x = (rA>>1)&3
  // lo 16B at rA*64 + ((2*l5)^x)*16 ; hi at rA*64 + ((2*l5+1)^x)*16
  int offAlo[2], offAhi[2], offBlo[2], offBhi[2];
#pragma unroll
  for (int mi = 0; mi < 2; ++mi) {
    const int rA = wr * 64 + mi * 32 + l31;
    const int xA = (rA >> 1) & 3;
    offAlo[mi] = rA * 64 + (((2 * l5) ^ xA) << 4);
    offAhi[mi] = rA * 64 + (((2 * l5 + 1) ^ xA) << 4);
    const int rB = wc * 64 + mi * 32 + l31;
    const int xB = (rB >> 1) & 3;
    offBlo[mi] = rB * 64 + (((2 * l5) ^ xB) << 4);
    offBhi[mi] = rB * 64 + (((2 * l5 + 1) ^ xB) << 4);
  }

  f32x16 acc[2][2];
#pragma unroll
  for (int mi = 0; mi < 2; ++mi)
#pragma unroll
    for (int ni = 0; ni < 2; ++ni)
#pragma unroll
      for (int j = 0; j < 16; ++j) acc[mi][ni][j] = 0.0f;

#define STAGE(kk)                                                      \
  {                                                                    \
    char* slot_ = ldsbuf + ((kk) & (RING - 1)) * SLOT_BYTES;           \
    const size_t koff_ = (size_t)(kk) * BK;                            \
    load_lds_16B(gA0 + koff_, slot_ + WA0);                            \
    load_lds_16B(gA1 + koff_, slot_ + WA1);                            \
    load_lds_16B(gB0 + koff_, slot_ + 8192 + WA0);                     \
    load_lds_16B(gB1 + koff_, slot_ + 8192 + WA1);                     \
  }

#define COMPUTE(kk)                                                          \
  {                                                                          \
    const char* slot_ = ldsbuf + ((kk) & (RING - 1)) * SLOT_BYTES;           \
    i32x8 af[2], bf[2];                                                      \
    _Pragma("unroll") for (int mi = 0; mi < 2; ++mi) {                       \
      i32x4 lo = *reinterpret_cast<const i32x4*>(slot_ + offAlo[mi]);        \
      i32x4 hi = *reinterpret_cast<const i32x4*>(slot_ + offAhi[mi]);        \
      af[mi] = __builtin_shufflevector(lo, hi, 0, 1, 2, 3, 4, 5, 6, 7);      \
    }                                                                        \
    _Pragma("unroll") for (int ni = 0; ni < 2; ++ni) {                       \
      i32x4 lo = *reinterpret_cast<const i32x4*>(slot_ + 8192 + offBlo[ni]); \
      i32x4 hi = *reinterpret_cast<const i32x4*>(slot_ + 8192 + offBhi[ni]); \
      bf[ni] = __builtin_shufflevector(lo, hi, 0, 1, 2, 3, 4, 5, 6, 7);      \
    }                                                                        \
    __builtin_amdgcn_s_setprio(1);                                          \
    _Pragma("unroll") for (int mi = 0; mi < 2; ++mi)                         \
        _Pragma("unroll") for (int ni = 0; ni < 2; ++ni) acc[mi][ni] =       \
            __builtin_amdgcn_mfma_scale_f32_32x32x64_f8f6f4(                 \
                af[mi], bf[ni], acc[mi][ni], 0, 0, 0, SCALE1, 0, SCALE1);    \
    __builtin_amdgcn_s_setprio(0);                                          \
  }

  // prologue
  STAGE(0);
  VMCNT0();
  BARRIER();

  // steady state: issue next tile's loads, compute current, wait, barrier
  for (int k = 0; k < NT - 1; ++k) {
    STAGE(k + 1);
    COMPUTE(k);
    VMCNT0();  // STAGE(k+1) was issued a full compute-phase ago
    BARRIER();
  }
  COMPUTE(NT - 1);

  // ---- epilogue: exp2 + row/col reductions ----
  // C/D layout (32x32): col = m0 + wc*64 + ni*32 + (lane&31)
  //                     row = row0 + wr*64 + mi*32 + (reg&3)+8*(reg>>2)+4*l5
  const float C2 = 2.8853900817779268f;  // 2*log2(e): exp(2x) = exp2(C2*x)
#pragma unroll
  for (int mi = 0; mi < 2; ++mi)
#pragma unroll
    for (int ni = 0; ni < 2; ++ni)
#pragma unroll
      for (int j = 0; j < 16; ++j)
        acc[mi][ni][j] = exp2f(acc[mi][ni][j] * C2);

  // row sums: fixed (mi, reg) -> sum over ni (in-lane) + 32-lane col group
#pragma unroll
  for (int mi = 0; mi < 2; ++mi) {
#pragma unroll
    for (int r = 0; r < 16; ++r) {
      float s = acc[mi][0][r] + acc[mi][1][r];
      s += __shfl_xor(s, 1, 64);
      s += __shfl_xor(s, 2, 64);
      s += __shfl_xor(s, 4, 64);
      s += __shfl_xor(s, 8, 64);
      s += __shfl_xor(s, 16, 64);
      if (l31 == 0)
        atomicAdd(&rowAcc[wr * 64 + mi * 32 + (r & 3) + 8 * (r >> 2) + 4 * l5],
                  s);
    }
  }

  // col sums (off-diagonal only): per ni, in-lane over mi+regs, fold halves
  if (!diag) {
#pragma unroll
    for (int ni = 0; ni < 2; ++ni) {
      float s = 0.0f;
#pragma unroll
      for (int mi = 0; mi < 2; ++mi)
#pragma unroll
        for (int r = 0; r < 16; ++r) s += acc[mi][ni][r];
      s += __shfl_xor(s, 32, 64);
      if (l5 == 0) atomicAdd(&colAcc[wc * 64 + ni * 32 + l31], s);
    }
  }

  LGKM0();   // drain own ds_atomics before the barrier
  BARRIER();
  if (tid < BM) partial[(size_t)(row0 + tid) * NSLOT + tj] = rowAcc[tid];
  if (!diag && tid >= BM && tid < 2 * BM)
    partial[(size_t)(m0 + tid - BM) * NSLOT + ti] = colAcc[tid - BM];
#undef STAGE
#undef COMPUTE
}

// ---------------------------------------------------------------------------
// Kernel 4a: per-row loss, block partial sums (32 blocks x 256 threads)
// ---------------------------------------------------------------------------
__global__ void rowloss_kernel(const float* __restrict__ partial,
                               const float* __restrict__ dn,
                               const float* __restrict__ pos,
                               float* __restrict__ blockSum) {
  const int tid = threadIdx.x;
  const int n = blockIdx.x * 256 + tid;  // 0..8191
  const float C2 = 2.8853900817779268f;
  float S = 0.0f;
#pragma unroll
  for (int c = 0; c < NSLOT; ++c) S += partial[(size_t)n * NSLOT + c];
  const float den = S - exp2f(dn[n] * C2);  // remove self-similarity term
  const float p = pos[(n < B_ROWS) ? n : (n - B_ROWS)];
  float acc = -2.0f * p + logf(den);
#pragma unroll
  for (int m = 32; m; m >>= 1) acc += __shfl_xor(acc, m, 64);
  __shared__ float red[4];
  const int wave = tid >> 6, lane = tid & 63;
  if (lane == 0) red[wave] = acc;
  __syncthreads();
  if (tid == 0) blockSum[blockIdx.x] = red[0] + red[1] + red[2] + red[3];
}

// ---------------------------------------------------------------------------
// Kernel 4b: reduce 32 block sums -> scalar loss
// ---------------------------------------------------------------------------
__global__ void final2_kernel(const float* __restrict__ blockSum,
                              float* __restrict__ out) {
  const int tid = threadIdx.x;  // 64
  float v = (tid < 32) ? blockSum[tid] : 0.0f;
#pragma unroll
  for (int m = 32; m; m >>= 1) v += __shfl_xor(v, m, 64);
  if (tid == 0) out[0] = v / (float)N_ROWS;
}

// ---------------------------------------------------------------------------
extern "C" void kernel_launch(void* const* d_in, const int* in_sizes, int n_in,
                              void* d_out, int out_size, void* d_ws,
                              size_t ws_size, hipStream_t stream) {
  const float* emb_i = (const float*)d_in[0];
  const float* emb_j = (const float*)d_in[1];
  float* out = (float*)d_out;

  // workspace layout
  unsigned char* z = (unsigned char*)d_ws;                        // 8 MB fp8
  char* p = (char*)d_ws + (size_t)N_ROWS * D_DIM;
  float* partial = (float*)p;                                     // 2 MB
  p += (size_t)N_ROWS * NSLOT * sizeof(float);
  float* dn = (float*)p;                                          // 32 KB
  p += (size_t)N_ROWS * sizeof(float);
  float* pos = (float*)p;                                         // 16 KB
  p += (size_t)B_ROWS * sizeof(float);
  float* blockSum = (float*)p;                                    // 128 B

  normalize_kernel<<<N_ROWS, 256, 0, stream>>>(emb_i, emb_j, z, dn);
  pos_kernel<<<B_ROWS, 256, 0, stream>>>(z, pos);
  simexp_kernel<<<NPAIRS, 256, 0, stream>>>(z, partial);
  rowloss_kernel<<<N_ROWS / 256, 256, 0, stream>>>(partial, dn, pos, blockSum);
  final2_kernel<<<1, 64, 0, stream>>>(blockSum, out);
}

// Round 7
// 258.534 us; speedup vs baseline: 1.4786x; 1.4786x over previous
//
#include <hip/hip_runtime.h>
#include <hip/hip_bf16.h>
#include <hip/hip_fp8.h>
#include <math.h>

// Problem constants
#define B_ROWS 4096
#define N_ROWS 8192          // 2B
#define D_DIM  1024
#define NTILES 64            // 8192 / 128
#define NSLOT  64            // partial slots per row = one per "other" tile
#define NPAIRS (NTILES * (NTILES + 1) / 2)  // 2080 upper-triangle tile pairs
#define NXCD 8

#define BM 128
#define BK 64                // fp8 elems per K-tile = 64 B per row
#define NT (D_DIM / BK)      // 16 K-tiles
#define SLOT_BYTES 16384     // A (8 KB) + B (8 KB) per ring slot
#define RING 2               // double buffer: 32 KB

typedef __attribute__((ext_vector_type(4))) int i32x4;
typedef __attribute__((ext_vector_type(8))) int i32x8;
typedef __attribute__((ext_vector_type(16))) float f32x16;

#define SCALE1 0x7F7F7F7F    // E8M0 127 = 2^0 in every byte -> unit scales

__device__ __forceinline__ void load_lds_16B(const void* g, void* l) {
  __builtin_amdgcn_global_load_lds(
      (const __attribute__((address_space(1))) void*)g,
      (__attribute__((address_space(3))) void*)l, 16, 0, 0);
}

#define VMCNT0() asm volatile("s_waitcnt vmcnt(0)" ::: "memory")
#define LGKM0()  asm volatile("s_waitcnt lgkmcnt(0)" ::: "memory")
#define BARRIER() asm volatile("s_barrier" ::: "memory")

__device__ __forceinline__ float fp8dec(unsigned char b) {
  __hip_fp8_e4m3 t;
  t.__x = b;
  return (float)t;
}

// ---------------------------------------------------------------------------
// Kernel 1: row L2-normalize -> fp8 e4m3 z [8192][1024]; dn[n] = sum(q(z)^2)
// ---------------------------------------------------------------------------
__global__ void normalize_kernel(const float* __restrict__ emb_i,
                                 const float* __restrict__ emb_j,
                                 unsigned char* __restrict__ z,
                                 float* __restrict__ dn) {
  const int row = blockIdx.x;
  const int tid = threadIdx.x;  // 256 threads, 4 floats each
  const float* src = (row < B_ROWS) ? (emb_i + (size_t)row * D_DIM)
                                    : (emb_j + (size_t)(row - B_ROWS) * D_DIM);
  float4 v = reinterpret_cast<const float4*>(src)[tid];
  float ss = v.x * v.x + v.y * v.y + v.z * v.z + v.w * v.w;
#pragma unroll
  for (int m = 32; m; m >>= 1) ss += __shfl_xor(ss, m, 64);
  __shared__ float red[4];
  const int wave = tid >> 6, lane = tid & 63;
  if (lane == 0) red[wave] = ss;
  __syncthreads();
  const float tot = red[0] + red[1] + red[2] + red[3];
  const float scale = 1.0f / fmaxf(sqrtf(tot), 1e-12f);

  __hip_fp8_e4m3 q0(v.x * scale), q1(v.y * scale), q2(v.z * scale),
      q3(v.w * scale);
  uchar4 pk;
  pk.x = q0.__x;
  pk.y = q1.__x;
  pk.z = q2.__x;
  pk.w = q3.__x;
  reinterpret_cast<uchar4*>(z)[(size_t)row * (D_DIM / 4) + tid] = pk;

  const float f0 = (float)q0, f1 = (float)q1, f2 = (float)q2, f3 = (float)q3;
  float ds = f0 * f0 + f1 * f1 + f2 * f2 + f3 * f3;
#pragma unroll
  for (int m = 32; m; m >>= 1) ds += __shfl_xor(ds, m, 64);
  __syncthreads();
  if (lane == 0) red[wave] = ds;
  __syncthreads();
  if (tid == 0) dn[row] = red[0] + red[1] + red[2] + red[3];
}

// ---------------------------------------------------------------------------
// Kernel 2: pos[n] = dot(q(z[n]), q(z[n+B])) for n in [0,B)
// ---------------------------------------------------------------------------
__global__ void pos_kernel(const unsigned char* __restrict__ z,
                           float* __restrict__ pos) {
  const int n = blockIdx.x;     // 0..4095
  const int tid = threadIdx.x;  // 256
  uchar4 a = reinterpret_cast<const uchar4*>(z + (size_t)n * D_DIM)[tid];
  uchar4 b =
      reinterpret_cast<const uchar4*>(z + (size_t)(n + B_ROWS) * D_DIM)[tid];
  float s = fp8dec(a.x) * fp8dec(b.x) + fp8dec(a.y) * fp8dec(b.y) +
            fp8dec(a.z) * fp8dec(b.z) + fp8dec(a.w) * fp8dec(b.w);
#pragma unroll
  for (int m = 32; m; m >>= 1) s += __shfl_xor(s, m, 64);
  __shared__ float red[4];
  const int wave = tid >> 6, lane = tid & 63;
  if (lane == 0) red[wave] = s;
  __syncthreads();
  if (tid == 0) pos[n] = red[0] + red[1] + red[2] + red[3];
}

// ---------------------------------------------------------------------------
// Kernel 3: fused fp8 GEMM + exp + row/col-sum, symmetric tile pairs.
// Same ring-2 schedule as R4/R5 (verified). Spill fixes vs R5:
//  - launch_bounds(256,3): VGPR cap ~168 (was 128 at min-4)
//  - named f32x16 accumulators (no array indexing anywhere)
//  - one live B-frag at a time; single per-lane base pointer + uniform deltas
// ---------------------------------------------------------------------------
__global__ __launch_bounds__(256, 3) void simexp_kernel(
    const unsigned char* __restrict__ z, float* __restrict__ partial) {
  __shared__ __align__(16) char ldsbuf[RING * SLOT_BYTES];  // 32 KB
  __shared__ float rowAcc[BM];
  __shared__ float colAcc[BM];

  const int tid = threadIdx.x;

  // XCD-chunked bijective swizzle (2080 = 8 * 260).
  const int work = (blockIdx.x % NXCD) * (NPAIRS / NXCD) + blockIdx.x / NXCD;

  // triangular decode: work -> (ti, tj), ti <= tj
  int rem = work;
  int ti = 0;
  while (rem >= NTILES - ti) {
    rem -= NTILES - ti;
    ++ti;
  }
  const int tj = ti + rem;
  const bool diag = (ti == tj);
  const int row0 = ti * BM;
  const int m0 = tj * BM;

  if (tid < BM) rowAcc[tid] = 0.0f;
  else colAcc[tid - BM] = 0.0f;

  const int wave = tid >> 6, lane = tid & 63;
  const int wr = wave >> 1, wc = wave & 1;  // 2x2 wave grid, each 64x64
  const int l31 = lane & 31, l5 = lane >> 5;

  // ---- staging geometry: one per-lane base + uniform deltas ----
  const int rs = tid >> 2;
  const int qs = tid & 3;
  const int ss = qs ^ ((rs >> 1) & 3);
  const unsigned char* gA0 = z + (size_t)(row0 + rs) * D_DIM + ss * 16;
  const size_t dR64 = (size_t)64 * D_DIM;           // +64 rows
  const size_t dB = (size_t)(m0 - row0) * D_DIM;    // A-panel -> B-panel
  const int WA0 = tid * 16;
  const int WA1 = tid * 16 + 4096;

  // ---- fragment read offsets (fixed per thread) ----
  // frag mi: row rA = wr*64 + mi*32 + l31; x = (rA>>1)&3
  // lo 16B at rA*64 + ((2*l5)^x)*16 ; hi at rA*64 + ((2*l5+1)^x)*16
  int offAlo0, offAhi0, offAlo1, offAhi1;
  int offBlo0, offBhi0, offBlo1, offBhi1;
  {
    int rA = wr * 64 + l31;
    int xA = (rA >> 1) & 3;
    offAlo0 = rA * 64 + (((2 * l5) ^ xA) << 4);
    offAhi0 = rA * 64 + (((2 * l5 + 1) ^ xA) << 4);
    rA = wr * 64 + 32 + l31;
    xA = (rA >> 1) & 3;
    offAlo1 = rA * 64 + (((2 * l5) ^ xA) << 4);
    offAhi1 = rA * 64 + (((2 * l5 + 1) ^ xA) << 4);
    int rB = wc * 64 + l31;
    int xB = (rB >> 1) & 3;
    offBlo0 = 8192 + rB * 64 + (((2 * l5) ^ xB) << 4);
    offBhi0 = 8192 + rB * 64 + (((2 * l5 + 1) ^ xB) << 4);
    rB = wc * 64 + 32 + l31;
    xB = (rB >> 1) & 3;
    offBlo1 = 8192 + rB * 64 + (((2 * l5) ^ xB) << 4);
    offBhi1 = 8192 + rB * 64 + (((2 * l5 + 1) ^ xB) << 4);
  }

  // named accumulators: accMN = wave-tile quadrant (mi=M rows, ni=N cols)
  f32x16 acc00, acc01, acc10, acc11;
#pragma unroll
  for (int j = 0; j < 16; ++j) {
    acc00[j] = 0.0f;
    acc01[j] = 0.0f;
    acc10[j] = 0.0f;
    acc11[j] = 0.0f;
  }

#define STAGE(kk)                                                      \
  {                                                                    \
    char* slot_ = ldsbuf + ((kk) & (RING - 1)) * SLOT_BYTES;           \
    const unsigned char* g_ = gA0 + (size_t)(kk)*BK;                   \
    load_lds_16B(g_, slot_ + WA0);                                     \
    load_lds_16B(g_ + dR64, slot_ + WA1);                              \
    load_lds_16B(g_ + dB, slot_ + 8192 + WA0);                         \
    load_lds_16B(g_ + dB + dR64, slot_ + 8192 + WA1);                  \
  }

#define LOAD8(dst, base, olo, ohi)                                     \
  {                                                                    \
    i32x4 lo_ = *reinterpret_cast<const i32x4*>((base) + (olo));       \
    i32x4 hi_ = *reinterpret_cast<const i32x4*>((base) + (ohi));       \
    dst = __builtin_shufflevector(lo_, hi_, 0, 1, 2, 3, 4, 5, 6, 7);   \
  }

#define COMPUTE(kk)                                                    \
  {                                                                    \
    const char* slot_ = ldsbuf + ((kk) & (RING - 1)) * SLOT_BYTES;     \
    i32x8 a0_, a1_, b_;                                                \
    LOAD8(a0_, slot_, offAlo0, offAhi0);                               \
    LOAD8(a1_, slot_, offAlo1, offAhi1);                               \
    LOAD8(b_, slot_, offBlo0, offBhi0);                                \
    __builtin_amdgcn_s_setprio(1);                                     \
    acc00 = __builtin_amdgcn_mfma_scale_f32_32x32x64_f8f6f4(           \
        a0_, b_, acc00, 0, 0, 0, SCALE1, 0, SCALE1);                   \
    acc10 = __builtin_amdgcn_mfma_scale_f32_32x32x64_f8f6f4(           \
        a1_, b_, acc10, 0, 0, 0, SCALE1, 0, SCALE1);                   \
    __builtin_amdgcn_s_setprio(0);                                     \
    LOAD8(b_, slot_, offBlo1, offBhi1);                                \
    __builtin_amdgcn_s_setprio(1);                                     \
    acc01 = __builtin_amdgcn_mfma_scale_f32_32x32x64_f8f6f4(           \
        a0_, b_, acc01, 0, 0, 0, SCALE1, 0, SCALE1);                   \
    acc11 = __builtin_amdgcn_mfma_scale_f32_32x32x64_f8f6f4(           \
        a1_, b_, acc11, 0, 0, 0, SCALE1, 0, SCALE1);                   \
    __builtin_amdgcn_s_setprio(0);                                     \
  }

  // prologue
  STAGE(0);
  VMCNT0();
  BARRIER();

  // steady state: issue next tile's loads, compute current, wait, barrier
  for (int k = 0; k < NT - 1; ++k) {
    STAGE(k + 1);
    COMPUTE(k);
    VMCNT0();  // STAGE(k+1) was issued a full compute-phase ago
    BARRIER();
  }
  COMPUTE(NT - 1);

  // ---- epilogue: exp2 + row/col reductions ----
  // C/D layout (32x32): col = base + ni*32 + (lane&31)
  //                     row = base + mi*32 + (r&3)+8*(r>>2)+4*l5
  const float C2 = 2.8853900817779268f;  // 2*log2(e): exp(2x) = exp2(C2*x)
#pragma unroll
  for (int j = 0; j < 16; ++j) {
    acc00[j] = exp2f(acc00[j] * C2);
    acc01[j] = exp2f(acc01[j] * C2);
    acc10[j] = exp2f(acc10[j] * C2);
    acc11[j] = exp2f(acc11[j] * C2);
  }

  // row sums: sum over ni (in-lane) + 32-lane col group
#define ROWSUM(aX, aY, mi)                                                  \
  _Pragma("unroll") for (int r = 0; r < 16; ++r) {                          \
    float s = aX[r] + aY[r];                                                \
    s += __shfl_xor(s, 1, 64);                                              \
    s += __shfl_xor(s, 2, 64);                                              \
    s += __shfl_xor(s, 4, 64);                                              \
    s += __shfl_xor(s, 8, 64);                                              \
    s += __shfl_xor(s, 16, 64);                                             \
    if (l31 == 0)                                                           \
      atomicAdd(                                                            \
          &rowAcc[wr * 64 + (mi)*32 + (r & 3) + 8 * (r >> 2) + 4 * l5], s); \
  }
  ROWSUM(acc00, acc01, 0);
  ROWSUM(acc10, acc11, 1);

  // col sums (off-diagonal only): in-lane over rows, fold lane halves
#define COLSUM(aX, aY, ni)                                             \
  {                                                                    \
    float s = 0.0f;                                                    \
    _Pragma("unroll") for (int r = 0; r < 16; ++r) s += aX[r] + aY[r]; \
    s += __shfl_xor(s, 32, 64);                                        \
    if (l5 == 0) atomicAdd(&colAcc[wc * 64 + (ni)*32 + l31], s);       \
  }
  if (!diag) {
    COLSUM(acc00, acc10, 0);
    COLSUM(acc01, acc11, 1);
  }

  LGKM0();   // drain own ds_atomics before the barrier
  BARRIER();
  if (tid < BM) partial[(size_t)(row0 + tid) * NSLOT + tj] = rowAcc[tid];
  if (!diag && tid >= BM && tid < 2 * BM)
    partial[(size_t)(m0 + tid - BM) * NSLOT + ti] = colAcc[tid - BM];
#undef STAGE
#undef LOAD8
#undef COMPUTE
#undef ROWSUM
#undef COLSUM
}

// ---------------------------------------------------------------------------
// Kernel 4a: per-row loss, block partial sums (32 blocks x 256 threads)
// ---------------------------------------------------------------------------
__global__ void rowloss_kernel(const float* __restrict__ partial,
                               const float* __restrict__ dn,
                               const float* __restrict__ pos,
                               float* __restrict__ blockSum) {
  const int tid = threadIdx.x;
  const int n = blockIdx.x * 256 + tid;  // 0..8191
  const float C2 = 2.8853900817779268f;
  float S = 0.0f;
#pragma unroll
  for (int c = 0; c < NSLOT; ++c) S += partial[(size_t)n * NSLOT + c];
  const float den = S - exp2f(dn[n] * C2);  // remove self-similarity term
  const float p = pos[(n < B_ROWS) ? n : (n - B_ROWS)];
  float acc = -2.0f * p + logf(den);
#pragma unroll
  for (int m = 32; m; m >>= 1) acc += __shfl_xor(acc, m, 64);
  __shared__ float red[4];
  const int wave = tid >> 6, lane = tid & 63;
  if (lane == 0) red[wave] = acc;
  __syncthreads();
  if (tid == 0) blockSum[blockIdx.x] = red[0] + red[1] + red[2] + red[3];
}

// ---------------------------------------------------------------------------
// Kernel 4b: reduce 32 block sums -> scalar loss
// ---------------------------------------------------------------------------
__global__ void final2_kernel(const float* __restrict__ blockSum,
                              float* __restrict__ out) {
  const int tid = threadIdx.x;  // 64
  float v = (tid < 32) ? blockSum[tid] : 0.0f;
#pragma unroll
  for (int m = 32; m; m >>= 1) v += __shfl_xor(v, m, 64);
  if (tid == 0) out[0] = v / (float)N_ROWS;
}

// ---------------------------------------------------------------------------
extern "C" void kernel_launch(void* const* d_in, const int* in_sizes, int n_in,
                              void* d_out, int out_size, void* d_ws,
                              size_t ws_size, hipStream_t stream) {
  const float* emb_i = (const float*)d_in[0];
  const float* emb_j = (const float*)d_in[1];
  float* out = (float*)d_out;

  // workspace layout
  unsigned char* z = (unsigned char*)d_ws;                        // 8 MB fp8
  char* p = (char*)d_ws + (size_t)N_ROWS * D_DIM;
  float* partial = (float*)p;                                     // 2 MB
  p += (size_t)N_ROWS * NSLOT * sizeof(float);
  float* dn = (float*)p;                                          // 32 KB
  p += (size_t)N_ROWS * sizeof(float);
  float* pos = (float*)p;                                         // 16 KB
  p += (size_t)B_ROWS * sizeof(float);
  float* blockSum = (float*)p;                                    // 128 B

  normalize_kernel<<<N_ROWS, 256, 0, stream>>>(emb_i, emb_j, z, dn);
  pos_kernel<<<B_ROWS, 256, 0, stream>>>(z, pos);
  simexp_kernel<<<NPAIRS, 256, 0, stream>>>(z, partial);
  rowloss_kernel<<<N_ROWS / 256, 256, 0, stream>>>(partial, dn, pos, blockSum);
  final2_kernel<<<1, 64, 0, stream>>>(blockSum, out);
}